// Round 1
// baseline (4194.206 us; speedup 1.0000x reference)
//
#include <hip/hip_runtime.h>

#define T_STEPS 512
#define HDIM 512

typedef __bf16 bf16x8 __attribute__((ext_vector_type(8)));
typedef float f32x4 __attribute__((ext_vector_type(4)));

union UQ { uint4 q; bf16x8 v; };

__device__ __forceinline__ unsigned short f2bf(float x){
  union { float f; unsigned u; } c; c.f = x;
  return (unsigned short)((c.u + 0x7fffu + ((c.u >> 16) & 1u)) >> 16);
}

// Pack W (512x512 f32 row-major, used as out = act @ W^T) into canonical MFMA
// B-fragment stream: dst[(ntile*16 + kt)*64 + lane] holds 8 bf16 =
// W[ntile*16 + (lane&15)][kt*32 + (lane>>4)*8 + j]   (B[k][n] = W[n][k])
__global__ void pack_kernel(const float* __restrict__ W, uint4* __restrict__ dst){
  int tid  = blockIdx.x * 512 + threadIdx.x;   // 0..32767
  int lane = tid & 63;
  int kt   = (tid >> 6) & 15;
  int ntl  = tid >> 10;
  int row  = ntl * 16 + (lane & 15);
  int k0   = kt * 32 + ((lane >> 4) << 3);
  const float* s = &W[row * 512 + k0];
  unsigned a0 = f2bf(s[0]) | ((unsigned)f2bf(s[1]) << 16);
  unsigned a1 = f2bf(s[2]) | ((unsigned)f2bf(s[3]) << 16);
  unsigned a2 = f2bf(s[4]) | ((unsigned)f2bf(s[5]) << 16);
  unsigned a3 = f2bf(s[6]) | ((unsigned)f2bf(s[7]) << 16);
  dst[tid] = (uint4){a0, a1, a2, a3};
}

// h0[b][n] = sum_o init[b][o] * Whi[n][o]
__global__ void h0_kernel(const float* __restrict__ init, const float* __restrict__ Whi,
                          float* __restrict__ h0){
  int b = blockIdx.x, n = threadIdx.x;  // 256 x 512
  __shared__ float ic[512];
  ic[n] = init[b * 512 + n];
  __syncthreads();
  const float4* wr = (const float4*)&Whi[n * 512];
  float s = 0.f;
  #pragma unroll 8
  for (int o = 0; o < 128; o++){
    float4 w = wr[o];
    s += w.x * ic[4*o] + w.y * ic[4*o+1] + w.z * ic[4*o+2] + w.w * ic[4*o+3];
  }
  h0[b * 512 + n] = s;
}

// Recurrence: 16 WGs x 512 threads (8 waves). WG g owns batches 16g..16g+15.
// Wave w owns output cols n in [64w, 64w+64). h kept f32 in registers
// (lane owns (b,n) slots stable across steps); bf16 swizzled copy in LDS
// feeds next step's A-fragments. W_rec streamed from L2 as fragments.
__global__ __launch_bounds__(512, 2)
void rnn_kernel(const float* __restrict__ inputs, const float* __restrict__ W_in,
                const float* __restrict__ b_in, const float* __restrict__ b_rec,
                const uint4* __restrict__ wfrag, const float* __restrict__ h0,
                float* __restrict__ hidden){
  const int g16  = blockIdx.x << 4;
  const int tid  = threadIdx.x;
  const int w    = tid >> 6;
  const int lane = tid & 63;
  const int col  = lane & 15;   // A: m(row)=batch-local ; B/C: n-local
  const int quad = lane >> 4;
  const int w4   = w << 2;

  __shared__ unsigned short hbf[16 * 512];  // swizzled bf16 h
  __shared__ float xin_s[32];               // [b_local][2]

  // per-lane constants for its 4 n-columns
  int   n_[4];  float win0[4], win1[4], bc[4];
  #pragma unroll
  for (int nt = 0; nt < 4; nt++){
    int n = (w << 6) + (nt << 4) + col;
    n_[nt] = n;
    win0[nt] = W_in[2*n];  win1[nt] = W_in[2*n + 1];
    bc[nt]   = b_in[n] + b_rec[n];
  }

  // init h (f32 regs) + initial bf16 LDS copy
  float h[4][4];
  #pragma unroll
  for (int nt = 0; nt < 4; nt++){
    #pragma unroll
    for (int r = 0; r < 4; r++){
      int b = (quad << 2) + r;
      float v = h0[(g16 + b) * 512 + n_[nt]];
      h[nt][r] = v;
      hbf[(b << 9) + (n_[nt] ^ ((b & 7) << 3))] = f2bf(v);
    }
  }
  __syncthreads();

  for (int t = 0; t < T_STEPS; t++){
    if (tid < 32)
      xin_s[tid] = inputs[((g16 + (tid >> 1)) * 512 + t) * 2 + (tid & 1)];

    // A-fragments from swizzled LDS: row=col(batch), k = kt*32 + quad*8 + j
    bf16x8 a[16];
    #pragma unroll
    for (int kt = 0; kt < 16; kt++){
      int idx = (col << 9) + (((kt << 5) + (quad << 3)) ^ ((col & 7) << 3));
      a[kt] = *(const bf16x8*)&hbf[idx];
    }
    __syncthreads();   // all A-reads done; xin visible

    f32x4 acc[4];
    #pragma unroll
    for (int nt = 0; nt < 4; nt++) acc[nt] = (f32x4){0.f, 0.f, 0.f, 0.f};

    #pragma unroll
    for (int kt = 0; kt < 16; kt++){
      #pragma unroll
      for (int nt = 0; nt < 4; nt++){
        UQ u; u.q = wfrag[(((w4 + nt) << 4) + kt) * 64 + lane];
        acc[nt] = __builtin_amdgcn_mfma_f32_16x16x32_bf16(a[kt], u.v, acc[nt], 0, 0, 0);
      }
    }

    // epilogue: z = acc + x_t + biases ; h = 0.9h + 0.1 tanh(z)
    float i0[4], i1[4];
    #pragma unroll
    for (int r = 0; r < 4; r++){
      i0[r] = xin_s[((quad << 2) + r) * 2];
      i1[r] = xin_s[((quad << 2) + r) * 2 + 1];
    }
    #pragma unroll
    for (int nt = 0; nt < 4; nt++){
      #pragma unroll
      for (int r = 0; r < 4; r++){
        float z  = acc[nt][r] + fmaf(i0[r], win0[nt], fmaf(i1[r], win1[nt], bc[nt]));
        float e  = __expf(2.0f * z);
        float th = 1.0f - 2.0f / (e + 1.0f);
        float hn = 0.9f * h[nt][r] + 0.1f * th;
        h[nt][r] = hn;
        int b = (quad << 2) + r;
        hidden[((g16 + b) * 512 + t) * 512 + n_[nt]] = hn;
        hbf[(b << 9) + (n_[nt] ^ ((b & 7) << 3))] = f2bf(hn);
      }
    }
    __syncthreads();   // hbf writes visible before next step's A-reads
  }
}

// outputs = hidden @ W_out^T : 1024 WGs x 8 waves; WG tile 128M x 512N (full N,
// hidden read exactly once). Wave: ms=w>>1 (32 rows), nh=w&1 (256 cols).
__global__ __launch_bounds__(512, 2)
void out_gemm(const float* __restrict__ hidden, const uint4* __restrict__ wofrag,
              float* __restrict__ outp){
  const int tid  = threadIdx.x;
  const int w    = tid >> 6;
  const int lane = tid & 63;
  const int col  = lane & 15;
  const int quad = lane >> 4;
  const int ms   = w >> 1;
  const int nh   = w & 1;
  const int m0   = blockIdx.x << 7;

  __shared__ unsigned short albf[128 * 32];  // swizzled bf16 A-tile

  f32x4 acc[2][16];
  #pragma unroll
  for (int mt = 0; mt < 2; mt++)
    #pragma unroll
    for (int nt = 0; nt < 16; nt++) acc[mt][nt] = (f32x4){0.f, 0.f, 0.f, 0.f};

  for (int kt = 0; kt < 16; kt++){
    // stage 128x32 f32 -> bf16 swizzled (XOR on byte bits 4-5 with row bits 1-2)
    #pragma unroll
    for (int i = 0; i < 2; i++){
      int r  = (tid >> 3) + (i << 6);
      int c4 = (tid & 7) << 2;
      float4 v = *(const float4*)&hidden[(m0 + r) * 512 + (kt << 5) + c4];
      unsigned lo = f2bf(v.x) | ((unsigned)f2bf(v.y) << 16);
      unsigned hi = f2bf(v.z) | ((unsigned)f2bf(v.w) << 16);
      int byteoff = (r << 6) + ((c4 << 1) ^ (((r >> 1) & 3) << 4));
      *(uint2*)((char*)albf + byteoff) = (uint2){lo, hi};
    }
    __syncthreads();

    bf16x8 af[2];
    #pragma unroll
    for (int mt = 0; mt < 2; mt++){
      int rl = (ms << 5) + (mt << 4) + col;
      int byteoff = (rl << 6) + ((quad << 4) ^ (((rl >> 1) & 3) << 4));
      af[mt] = *(const bf16x8*)((const char*)albf + byteoff);
    }

    #pragma unroll
    for (int nt = 0; nt < 16; nt++){
      UQ u; u.q = wofrag[((((nh << 4) + nt) << 4) + kt) * 64 + lane];
      acc[0][nt] = __builtin_amdgcn_mfma_f32_16x16x32_bf16(af[0], u.v, acc[0][nt], 0, 0, 0);
      acc[1][nt] = __builtin_amdgcn_mfma_f32_16x16x32_bf16(af[1], u.v, acc[1][nt], 0, 0, 0);
    }
    __syncthreads();
  }

  #pragma unroll
  for (int mt = 0; mt < 2; mt++)
    #pragma unroll
    for (int nt = 0; nt < 16; nt++)
      #pragma unroll
      for (int r = 0; r < 4; r++)
        outp[(m0 + (ms << 5) + (mt << 4) + (quad << 2) + r) * 512
             + (nh << 8) + (nt << 4) + col] = acc[mt][nt][r];
}

extern "C" void kernel_launch(void* const* d_in, const int* in_sizes, int n_in,
                              void* d_out, int out_size, void* d_ws, size_t ws_size,
                              hipStream_t stream){
  const float* inputs  = (const float*)d_in[0];  // (256,512,2)
  const float* initc   = (const float*)d_in[1];  // (256,512)
  const float* W_in    = (const float*)d_in[2];  // (512,2)
  const float* b_in    = (const float*)d_in[3];  // (512)
  const float* W_rec   = (const float*)d_in[4];  // (512,512)
  const float* b_rec   = (const float*)d_in[5];  // (512)
  const float* W_out   = (const float*)d_in[6];  // (512,512)
  const float* W_hi    = (const float*)d_in[7];  // (512,512)

  float* hidden  = (float*)d_out;                 // 256*512*512
  float* outputs = hidden + (size_t)67108864;     // second half

  char* ws = (char*)d_ws;
  uint4* wrec_f = (uint4*)ws;                     // 512 KB
  uint4* wout_f = (uint4*)(ws + (512 << 10));     // 512 KB
  float* h0     = (float*)(ws + (1 << 20));       // 512 KB

  pack_kernel<<<64, 512, 0, stream>>>(W_rec, wrec_f);
  pack_kernel<<<64, 512, 0, stream>>>(W_out, wout_f);
  h0_kernel<<<256, 512, 0, stream>>>(initc, W_hi, h0);
  rnn_kernel<<<16, 512, 0, stream>>>(inputs, W_in, b_in, b_rec, wrec_f, h0, hidden);
  out_gemm<<<1024, 512, 0, stream>>>(hidden, wout_f, outputs);
}